// Round 6
// baseline (81.120 us; speedup 1.0000x reference)
//
#include <hip/hip_runtime.h>
#include <math.h>

// QuantumNATHybridModel: pool(6x6) -> linear(16->4) -> 4-qubit circuit -> BatchNorm1d
// out[b,q] = r^T A_q r; A_q fixed 16x16 from qparams, r from per-sample RX angles.
// R5 lesson: perf scales with resident waves, invariant to per-wave work/pipelining.
// R6: 32 waves/CU — __launch_bounds__(256,8), VGPR<=64 (A-rows + weights in LDS),
// 2048 blocks fully resident, 1-deep rolling prefetch.

#define BATCH 65536
#define SPW 8                             // samples per wave
#define MAIN_BLOCKS (BATCH / (4 * SPW))   // 2048 blocks of 256 threads (4 waves)

// ---------------------------------------------------------------------------
// Precompute: build U (16x16 complex) from qparams, then A_q (4x16x16 real).
// Also zeroes the 8-double stats accumulator.
// ---------------------------------------------------------------------------
__global__ __launch_bounds__(256) void qnat_precompute(const float* __restrict__ qp,
                                                       float* __restrict__ A,
                                                       double* __restrict__ acc) {
  __shared__ float Ur[16][17], Ui[16][17];
  const int tid = threadIdx.x;
  if (tid >= 64 && tid < 72) acc[tid - 64] = 0.0;
  if (tid < 16) {
    const int col = tid;
    float ur[16], ui[16];
#pragma unroll
    for (int i = 0; i < 16; i++) { ur[i] = (i == col) ? 1.f : 0.f; ui[i] = 0.f; }
#pragma unroll
    for (int l = 0; l < 3; l++) {
#pragma unroll
      for (int q = 0; q < 4; q++) {
        const int b = 3 - q;  // qubit q lives on bit (3-q)
        const float ty = qp[(l * 4 + q) * 3 + 0];
        const float tz = qp[(l * 4 + q) * 3 + 1];
        const float cy = cosf(0.5f * ty), sy = sinf(0.5f * ty);
#pragma unroll
        for (int i0 = 0; i0 < 16; i0++) {
          if (((i0 >> b) & 1) == 0) {
            const int i1 = i0 | (1 << b);
            const float r0 = ur[i0], m0 = ui[i0], r1 = ur[i1], m1 = ui[i1];
            ur[i0] = cy * r0 - sy * r1;  ui[i0] = cy * m0 - sy * m1;
            ur[i1] = sy * r0 + cy * r1;  ui[i1] = sy * m0 + cy * m1;
          }
        }
        const float cz = cosf(0.5f * tz), sz = sinf(0.5f * tz);
#pragma unroll
        for (int i0 = 0; i0 < 16; i0++) {
          if (((i0 >> b) & 1) == 0) {
            const int i1 = i0 | (1 << b);
            const float r0 = ur[i0], m0 = ui[i0], r1 = ur[i1], m1 = ui[i1];
            ur[i0] = cz * r0 + sz * m0;  ui[i0] = cz * m0 - sz * r0;
            ur[i1] = cz * r1 - sz * m1;  ui[i1] = cz * m1 + sz * r1;
          }
        }
      }
      const int cb[4] = {3, 2, 1, 0};
      const int tb[4] = {2, 1, 0, 3};
#pragma unroll
      for (int e = 0; e < 4; e++) {
#pragma unroll
        for (int i = 0; i < 16; i++) {
          if (((i >> cb[e]) & 1) && (((i >> tb[e]) & 1) == 0)) {
            const int j2 = i | (1 << tb[e]);
            float t0 = ur[i]; ur[i] = ur[j2]; ur[j2] = t0;
            float t1 = ui[i]; ui[i] = ui[j2]; ui[j2] = t1;
          }
        }
      }
    }
#pragma unroll
    for (int i = 0; i < 16; i++) { Ur[i][col] = ur[i]; Ui[i][col] = ui[i]; }
  }
  __syncthreads();
  const int j = tid >> 4, k = tid & 15;
#pragma unroll
  for (int q = 0; q < 4; q++) {
    const int b = 3 - q;
    float mr = 0.f, mi = 0.f;
#pragma unroll
    for (int i = 0; i < 16; i++) {
      const float z = ((i >> b) & 1) ? -1.f : 1.f;
      const float ar = Ur[i][j], ai = Ui[i][j], br = Ur[i][k], bi = Ui[i][k];
      mr += z * (ar * br + ai * bi);
      mi += z * (ar * bi - ai * br);
    }
    const int e = (__popc((unsigned)j) - __popc((unsigned)k)) & 3;
    A[(q << 8) + tid] = (e == 0) ? mr : (e == 1) ? -mi : (e == 2) ? -mr : mi;
  }
}

// ---------------------------------------------------------------------------
// Main kernel: 32 waves/CU, rolling 1-deep prefetch, A + weights in LDS.
// ---------------------------------------------------------------------------
__global__ __launch_bounds__(256, 8) void qnat_main(const float* __restrict__ x,
                                                    const float* __restrict__ enc_w,
                                                    const float* __restrict__ enc_b,
                                                    const float* __restrict__ A,
                                                    float* __restrict__ out,
                                                    double* __restrict__ acc) {
  __shared__ float4 sW4[16];
  __shared__ float sA[4][16][17];    // +1 pad: 2-way bank conflict max (free)
  __shared__ double sAcc[4][4][2];   // [wave][q][{sum,sumsq}]
  const int tid = threadIdx.x;
  if (tid < 16) {
    const float inv36 = 1.0f / 36.0f;
    sW4[tid] = make_float4(enc_w[tid] * inv36, enc_w[16 + tid] * inv36,
                           enc_w[32 + tid] * inv36, enc_w[48 + tid] * inv36);
  }
#pragma unroll
  for (int m = 0; m < 4; m++) {       // copy A (1024 floats) into padded LDS
    const int idx = tid * 4 + m;
    sA[idx >> 8][(idx >> 4) & 15][idx & 15] = A[idx];
  }
  __syncthreads();

  const int wave = tid >> 6, lane = tid & 63;
  const int j = lane & 15;        // row of A within 16-lane group
  const int g = lane >> 4;        // which qubit's A this group owns
  const bool bit0 = lane & 1, bit1 = lane & 2;
  const float* Arow = &sA[g][j][0];

  // Paired pool-weight LDS indices (6-col cell boundary splits any float4 2+2).
  int iX[3], iY[3];
#pragma unroll
  for (int t = 0; t < 3; t++) {
    int p0 = t * 256 + 4 * lane;
    if (p0 > 572) p0 = 572;
    const int row = p0 / 24, col = p0 - row * 24;
    const int rr = (row / 6) * 4;
    iX[t] = rr + col / 6;
    iY[t] = rr + (col + 3) / 6;
  }
  const float bq = enc_b[lane & 3];

  const int s0 = (blockIdx.x * 4 + wave) * SPW;
  double sd = 0.0, ssd = 0.0;

  auto LOADB = [&](float4& V0, float4& V1, float4& V2, int S) {
    const float4* p4 = (const float4*)(x + (size_t)S * 576);
    V0 = p4[lane];
    V1 = p4[64 + lane];
    V2 = (lane < 16) ? p4[128 + lane] : make_float4(0.f, 0.f, 0.f, 0.f);
  };

  auto COMPUTE = [&](const float4& V0, const float4& V1, const float4& V2, int s) {
    float a0 = 0.f, a1 = 0.f, a2 = 0.f, a3 = 0.f;
#define ACCT(V, T)                                           \
    {                                                        \
      const float4 wX = sW4[iX[T]], wY = sW4[iY[T]];         \
      const float h0 = V.x + V.y, h1 = V.z + V.w;            \
      a0 = fmaf(h0, wX.x, fmaf(h1, wY.x, a0));               \
      a1 = fmaf(h0, wX.y, fmaf(h1, wY.y, a1));               \
      a2 = fmaf(h0, wX.z, fmaf(h1, wY.z, a2));               \
      a3 = fmaf(h0, wX.w, fmaf(h1, wY.w, a3));               \
    }
    ACCT(V0, 0) ACCT(V1, 1) ACCT(V2, 2)
#undef ACCT
    // Rotation fold: distribute the 4 angle sums across lane&3 while reducing.
    float snd, rcv;
    snd = bit0 ? a0 : a1; rcv = __shfl_xor(snd, 1);
    float Af = (bit0 ? a1 : a0) + rcv;
    snd = bit0 ? a2 : a3; rcv = __shfl_xor(snd, 1);
    float Bf = (bit0 ? a3 : a2) + rcv;
    snd = bit1 ? Af : Bf; rcv = __shfl_xor(snd, 2);
    float Cf = (bit1 ? Bf : Af) + rcv;
    Cf += __shfl_xor(Cf, 4);
    Cf += __shfl_xor(Cf, 8);
    Cf += __shfl_xor(Cf, 16);
    Cf += __shfl_xor(Cf, 32);                    // theta_{lane&3}

    float sm, cm;
    __sincosf(0.5f * (Cf + bq), &sm, &cm);       // one sincos per lane

    const int base = lane & ~3;
    const float c0 = __shfl(cm, base + 0), s0_ = __shfl(sm, base + 0);
    const float c1 = __shfl(cm, base + 1), s1_ = __shfl(sm, base + 1);
    const float c2 = __shfl(cm, base + 2), s2_ = __shfl(sm, base + 2);
    const float c3 = __shfl(cm, base + 3), s3_ = __shfl(sm, base + 3);

    const float p01[4] = {c0 * c1, c0 * s1_, s0_ * c1, s0_ * s1_};
    const float p23[4] = {c2 * c3, c2 * s3_, s2_ * c3, s2_ * s3_};
    float inner = 0.f;
#pragma unroll
    for (int hi = 0; hi < 4; hi++) {
      float sh = 0.f;
#pragma unroll
      for (int lo = 0; lo < 4; lo++) sh = fmaf(Arow[4 * hi + lo], p23[lo], sh);
      inner = fmaf(p01[hi], sh, inner);
    }
    const float rj = ((j & 8) ? s0_ : c0) * ((j & 4) ? s1_ : c1) *
                     ((j & 2) ? s2_ : c2) * ((j & 1) ? s3_ : c3);
    float v = inner * rj;
    v += __shfl_xor(v, 1);
    v += __shfl_xor(v, 2);
    v += __shfl_xor(v, 4);
    v += __shfl_xor(v, 8);
    if (j == 0) {
      out[(size_t)s * 4 + g] = v;
      sd += (double)v;
      ssd = fma((double)v, (double)v, ssd);
    }
  };

  // Rolling 1-deep pipeline, statically named buffers (loads issue before compute).
  float4 A0, A1, A2, B0, B1, B2;
  LOADB(A0, A1, A2, s0 + 0);
  LOADB(B0, B1, B2, s0 + 1); COMPUTE(A0, A1, A2, s0 + 0);
  LOADB(A0, A1, A2, s0 + 2); COMPUTE(B0, B1, B2, s0 + 1);
  LOADB(B0, B1, B2, s0 + 3); COMPUTE(A0, A1, A2, s0 + 2);
  LOADB(A0, A1, A2, s0 + 4); COMPUTE(B0, B1, B2, s0 + 3);
  LOADB(B0, B1, B2, s0 + 5); COMPUTE(A0, A1, A2, s0 + 4);
  LOADB(A0, A1, A2, s0 + 6); COMPUTE(B0, B1, B2, s0 + 5);
  LOADB(B0, B1, B2, s0 + 7); COMPUTE(A0, A1, A2, s0 + 6);
  COMPUTE(B0, B1, B2, s0 + 7);

  if (j == 0) { sAcc[wave][g][0] = sd; sAcc[wave][g][1] = ssd; }
  __syncthreads();
  if (tid < 8) {  // tid = m*4 + q
    const int q = tid & 3, m = tid >> 2;
    const double t = sAcc[0][q][m] + sAcc[1][q][m] + sAcc[2][q][m] + sAcc[3][q][m];
    atomicAdd(&acc[m * 4 + q], t);
  }
}

// ---------------------------------------------------------------------------
// Normalize in place: out = (raw - mean)/sqrt(var+eps)*gamma + beta
// ---------------------------------------------------------------------------
__global__ __launch_bounds__(256) void qnat_norm(float* __restrict__ out,
                                                 const double* __restrict__ acc,
                                                 const float* __restrict__ gamma,
                                                 const float* __restrict__ beta) {
  __shared__ float sMean[4], sScale[4], sBeta[4];
  const int tid = threadIdx.x;
  if (tid < 4) {
    const double n = (double)BATCH;
    const double mean = acc[tid] / n;
    const double var = acc[4 + tid] / n - mean * mean;
    const double inv = 1.0 / sqrt(var + 1e-5);
    sMean[tid] = (float)mean;
    sScale[tid] = (float)(gamma[tid] * inv);
    sBeta[tid] = beta[tid];
  }
  __syncthreads();
  const size_t i = (size_t)blockIdx.x * 256 + tid;  // 65536 float4s, 256 blocks
  float4 v = ((const float4*)out)[i];
  v.x = (v.x - sMean[0]) * sScale[0] + sBeta[0];
  v.y = (v.y - sMean[1]) * sScale[1] + sBeta[1];
  v.z = (v.z - sMean[2]) * sScale[2] + sBeta[2];
  v.w = (v.w - sMean[3]) * sScale[3] + sBeta[3];
  ((float4*)out)[i] = v;
}

extern "C" void kernel_launch(void* const* d_in, const int* in_sizes, int n_in,
                              void* d_out, int out_size, void* d_ws, size_t ws_size,
                              hipStream_t stream) {
  const float* x       = (const float*)d_in[0];
  const float* enc_w   = (const float*)d_in[1];
  const float* enc_b   = (const float*)d_in[2];
  const float* qparams = (const float*)d_in[3];
  const float* gamma   = (const float*)d_in[4];
  const float* beta    = (const float*)d_in[5];
  float* out = (float*)d_out;

  float* A = (float*)d_ws;                          // 4*16*16 floats = 4 KB
  double* acc = (double*)((char*)d_ws + 4096);      // 8 doubles

  qnat_precompute<<<1, 256, 0, stream>>>(qparams, A, acc);
  qnat_main<<<MAIN_BLOCKS, 256, 0, stream>>>(x, enc_w, enc_b, A, out, acc);
  qnat_norm<<<256, 256, 0, stream>>>(out, acc, gamma, beta);
}

// Round 7
// 63.883 us; speedup vs baseline: 1.2698x; 1.2698x over previous
//
#include <hip/hip_runtime.h>
#include <math.h>

// QuantumNATHybridModel: pool(6x6) -> linear(16->4) -> 4-qubit circuit -> BatchNorm1d
// out[b,q] = r^T A_q r; A_q fixed 16x16 from qparams, r from per-sample RX angles.
// R6 lesson: (256,8) bound caused 64MB scratch spill (VGPR 32 + WRITE_SIZE 65MB).
// R7: global_load_lds staging — block stages 32 samples (72KB) into LDS via async
// DMA (no dest VGPRs, no spill), one barrier, compute from LDS. 2 blocks/CU.

#define BATCH 65536
#define SPB 32                            // samples per block
#define MAIN_BLOCKS (BATCH / SPB)         // 2048 blocks of 256 threads
#define TILE_BYTES (SPB * 576 * 4)        // 73728 B staged per block

#define AS1C(p) (const __attribute__((address_space(1))) void*)(p)
#define AS3(p)  (__attribute__((address_space(3))) void*)(p)

// ---------------------------------------------------------------------------
// Precompute: build U (16x16 complex) from qparams, then A_q (4x16x16 real).
// Also zeroes the 8-double stats accumulator.
// ---------------------------------------------------------------------------
__global__ __launch_bounds__(256) void qnat_precompute(const float* __restrict__ qp,
                                                       float* __restrict__ A,
                                                       double* __restrict__ acc) {
  __shared__ float Ur[16][17], Ui[16][17];
  const int tid = threadIdx.x;
  if (tid >= 64 && tid < 72) acc[tid - 64] = 0.0;
  if (tid < 16) {
    const int col = tid;
    float ur[16], ui[16];
#pragma unroll
    for (int i = 0; i < 16; i++) { ur[i] = (i == col) ? 1.f : 0.f; ui[i] = 0.f; }
#pragma unroll
    for (int l = 0; l < 3; l++) {
#pragma unroll
      for (int q = 0; q < 4; q++) {
        const int b = 3 - q;  // qubit q lives on bit (3-q)
        const float ty = qp[(l * 4 + q) * 3 + 0];
        const float tz = qp[(l * 4 + q) * 3 + 1];
        const float cy = cosf(0.5f * ty), sy = sinf(0.5f * ty);
#pragma unroll
        for (int i0 = 0; i0 < 16; i0++) {
          if (((i0 >> b) & 1) == 0) {
            const int i1 = i0 | (1 << b);
            const float r0 = ur[i0], m0 = ui[i0], r1 = ur[i1], m1 = ui[i1];
            ur[i0] = cy * r0 - sy * r1;  ui[i0] = cy * m0 - sy * m1;
            ur[i1] = sy * r0 + cy * r1;  ui[i1] = sy * m0 + cy * m1;
          }
        }
        const float cz = cosf(0.5f * tz), sz = sinf(0.5f * tz);
#pragma unroll
        for (int i0 = 0; i0 < 16; i0++) {
          if (((i0 >> b) & 1) == 0) {
            const int i1 = i0 | (1 << b);
            const float r0 = ur[i0], m0 = ui[i0], r1 = ur[i1], m1 = ui[i1];
            ur[i0] = cz * r0 + sz * m0;  ui[i0] = cz * m0 - sz * r0;
            ur[i1] = cz * r1 - sz * m1;  ui[i1] = cz * m1 + sz * r1;
          }
        }
      }
      const int cb[4] = {3, 2, 1, 0};
      const int tb[4] = {2, 1, 0, 3};
#pragma unroll
      for (int e = 0; e < 4; e++) {
#pragma unroll
        for (int i = 0; i < 16; i++) {
          if (((i >> cb[e]) & 1) && (((i >> tb[e]) & 1) == 0)) {
            const int j2 = i | (1 << tb[e]);
            float t0 = ur[i]; ur[i] = ur[j2]; ur[j2] = t0;
            float t1 = ui[i]; ui[i] = ui[j2]; ui[j2] = t1;
          }
        }
      }
    }
#pragma unroll
    for (int i = 0; i < 16; i++) { Ur[i][col] = ur[i]; Ui[i][col] = ui[i]; }
  }
  __syncthreads();
  const int j = tid >> 4, k = tid & 15;
#pragma unroll
  for (int q = 0; q < 4; q++) {
    const int b = 3 - q;
    float mr = 0.f, mi = 0.f;
#pragma unroll
    for (int i = 0; i < 16; i++) {
      const float z = ((i >> b) & 1) ? -1.f : 1.f;
      const float ar = Ur[i][j], ai = Ui[i][j], br = Ur[i][k], bi = Ui[i][k];
      mr += z * (ar * br + ai * bi);
      mi += z * (ar * bi - ai * br);
    }
    const int e = (__popc((unsigned)j) - __popc((unsigned)k)) & 3;
    A[(q << 8) + tid] = (e == 0) ? mr : (e == 1) ? -mi : (e == 2) ? -mr : mi;
  }
}

// ---------------------------------------------------------------------------
// Main kernel: async-DMA stage 72KB/block into LDS, one barrier, compute.
// ---------------------------------------------------------------------------
__global__ __launch_bounds__(256, 2) void qnat_main(const float* __restrict__ x,
                                                    const float* __restrict__ enc_w,
                                                    const float* __restrict__ enc_b,
                                                    const float* __restrict__ A,
                                                    float* __restrict__ out,
                                                    double* __restrict__ acc) {
  __shared__ float sX[SPB * 576];    // 73728 B, linear [sample][576]
  __shared__ float4 sW4[16];
  __shared__ double sAcc[4][4][2];   // [wave][q][{sum,sumsq}]
  const int tid = threadIdx.x;
  const int wave = tid >> 6, lane = tid & 63;

  // ---- stage: 18 x 1KB chunks per wave, chunk-interleaved, issued first ----
  {
    const char* xb = (const char*)x + (size_t)blockIdx.x * TILE_BYTES;
#pragma unroll
    for (int i = 0; i < 18; i++) {
      const int off = (i * 4 + wave) << 10;   // wave-uniform byte offset
      __builtin_amdgcn_global_load_lds(AS1C(xb + off + lane * 16),
                                       AS3((char*)sX + off), 16, 0, 0);
    }
  }

  if (tid < 16) {
    const float inv36 = 1.0f / 36.0f;
    sW4[tid] = make_float4(enc_w[tid] * inv36, enc_w[16 + tid] * inv36,
                           enc_w[32 + tid] * inv36, enc_w[48 + tid] * inv36);
  }

  const int j = lane & 15;        // row of A within 16-lane group
  const int g = lane >> 4;        // which qubit's A this group owns
  const bool bit0 = lane & 1, bit1 = lane & 2;

  // A row for this lane's (g, j): 16 registers (budget is roomy at 2 blocks/CU)
  float Areg[16];
#pragma unroll
  for (int k = 0; k < 16; k++) Areg[k] = A[(g << 8) + (j << 4) + k];
  const float bq = enc_b[lane & 3];

  __syncthreads();   // drains the DMA queue (vmcnt 0) + joins sW4 writers

  // Paired pool weights (6-col cell boundary splits any float4 as 2+2).
  float4 wXr[3], wYr[3];
#pragma unroll
  for (int t = 0; t < 3; t++) {
    int p0 = t * 256 + 4 * lane;
    if (p0 > 572) p0 = 572;
    const int row = p0 / 24, col = p0 - row * 24;
    const int rr = (row / 6) * 4;
    wXr[t] = sW4[rr + col / 6];
    wYr[t] = sW4[rr + (col + 3) / 6];
  }

  double sd = 0.0, ssd = 0.0;

#pragma unroll
  for (int i = 0; i < 8; i++) {
    const int sl = wave * 8 + i;                 // local sample
    const int s = blockIdx.x * SPB + sl;         // global sample
    const float4* p4 = (const float4*)(sX + sl * 576);
    const float4 V0 = p4[lane];
    const float4 V1 = p4[64 + lane];
    const float4 V2 = (lane < 16) ? p4[128 + lane] : make_float4(0.f, 0.f, 0.f, 0.f);

    float a0 = 0.f, a1 = 0.f, a2 = 0.f, a3 = 0.f;
#define ACCT(V, T)                                           \
    {                                                        \
      const float h0 = V.x + V.y, h1 = V.z + V.w;            \
      a0 = fmaf(h0, wXr[T].x, fmaf(h1, wYr[T].x, a0));       \
      a1 = fmaf(h0, wXr[T].y, fmaf(h1, wYr[T].y, a1));       \
      a2 = fmaf(h0, wXr[T].z, fmaf(h1, wYr[T].z, a2));       \
      a3 = fmaf(h0, wXr[T].w, fmaf(h1, wYr[T].w, a3));       \
    }
    ACCT(V0, 0) ACCT(V1, 1) ACCT(V2, 2)
#undef ACCT

    // Rotation fold: distribute the 4 angle sums across lane&3 while reducing.
    float snd, rcv;
    snd = bit0 ? a0 : a1; rcv = __shfl_xor(snd, 1);
    float Af = (bit0 ? a1 : a0) + rcv;
    snd = bit0 ? a2 : a3; rcv = __shfl_xor(snd, 1);
    float Bf = (bit0 ? a3 : a2) + rcv;
    snd = bit1 ? Af : Bf; rcv = __shfl_xor(snd, 2);
    float Cf = (bit1 ? Bf : Af) + rcv;
    Cf += __shfl_xor(Cf, 4);
    Cf += __shfl_xor(Cf, 8);
    Cf += __shfl_xor(Cf, 16);
    Cf += __shfl_xor(Cf, 32);                    // theta_{lane&3}

    float sm, cm;
    __sincosf(0.5f * (Cf + bq), &sm, &cm);       // one sincos per lane

    const int base = lane & ~3;
    const float c0 = __shfl(cm, base + 0), s0_ = __shfl(sm, base + 0);
    const float c1 = __shfl(cm, base + 1), s1_ = __shfl(sm, base + 1);
    const float c2 = __shfl(cm, base + 2), s2_ = __shfl(sm, base + 2);
    const float c3 = __shfl(cm, base + 3), s3_ = __shfl(sm, base + 3);

    const float p01[4] = {c0 * c1, c0 * s1_, s0_ * c1, s0_ * s1_};
    const float p23[4] = {c2 * c3, c2 * s3_, s2_ * c3, s2_ * s3_};
    float inner = 0.f;
#pragma unroll
    for (int hi = 0; hi < 4; hi++) {
      float sh = 0.f;
#pragma unroll
      for (int lo = 0; lo < 4; lo++) sh = fmaf(Areg[4 * hi + lo], p23[lo], sh);
      inner = fmaf(p01[hi], sh, inner);
    }
    const float rj = ((j & 8) ? s0_ : c0) * ((j & 4) ? s1_ : c1) *
                     ((j & 2) ? s2_ : c2) * ((j & 1) ? s3_ : c3);
    float v = inner * rj;
    v += __shfl_xor(v, 1);
    v += __shfl_xor(v, 2);
    v += __shfl_xor(v, 4);
    v += __shfl_xor(v, 8);
    if (j == 0) {
      out[(size_t)s * 4 + g] = v;
      sd += (double)v;
      ssd = fma((double)v, (double)v, ssd);
    }
  }

  if (j == 0) { sAcc[wave][g][0] = sd; sAcc[wave][g][1] = ssd; }
  __syncthreads();
  if (tid < 8) {  // tid = m*4 + q
    const int q = tid & 3, m = tid >> 2;
    const double t = sAcc[0][q][m] + sAcc[1][q][m] + sAcc[2][q][m] + sAcc[3][q][m];
    atomicAdd(&acc[m * 4 + q], t);
  }
}

// ---------------------------------------------------------------------------
// Normalize in place: out = (raw - mean)/sqrt(var+eps)*gamma + beta
// ---------------------------------------------------------------------------
__global__ __launch_bounds__(256) void qnat_norm(float* __restrict__ out,
                                                 const double* __restrict__ acc,
                                                 const float* __restrict__ gamma,
                                                 const float* __restrict__ beta) {
  __shared__ float sMean[4], sScale[4], sBeta[4];
  const int tid = threadIdx.x;
  if (tid < 4) {
    const double n = (double)BATCH;
    const double mean = acc[tid] / n;
    const double var = acc[4 + tid] / n - mean * mean;
    const double inv = 1.0 / sqrt(var + 1e-5);
    sMean[tid] = (float)mean;
    sScale[tid] = (float)(gamma[tid] * inv);
    sBeta[tid] = beta[tid];
  }
  __syncthreads();
  const size_t i = (size_t)blockIdx.x * 256 + tid;  // 65536 float4s, 256 blocks
  float4 v = ((const float4*)out)[i];
  v.x = (v.x - sMean[0]) * sScale[0] + sBeta[0];
  v.y = (v.y - sMean[1]) * sScale[1] + sBeta[1];
  v.z = (v.z - sMean[2]) * sScale[2] + sBeta[2];
  v.w = (v.w - sMean[3]) * sScale[3] + sBeta[3];
  ((float4*)out)[i] = v;
}

extern "C" void kernel_launch(void* const* d_in, const int* in_sizes, int n_in,
                              void* d_out, int out_size, void* d_ws, size_t ws_size,
                              hipStream_t stream) {
  const float* x       = (const float*)d_in[0];
  const float* enc_w   = (const float*)d_in[1];
  const float* enc_b   = (const float*)d_in[2];
  const float* qparams = (const float*)d_in[3];
  const float* gamma   = (const float*)d_in[4];
  const float* beta    = (const float*)d_in[5];
  float* out = (float*)d_out;

  float* A = (float*)d_ws;                          // 4*16*16 floats = 4 KB
  double* acc = (double*)((char*)d_ws + 4096);      // 8 doubles

  qnat_precompute<<<1, 256, 0, stream>>>(qparams, A, acc);
  qnat_main<<<MAIN_BLOCKS, 256, 0, stream>>>(x, enc_w, enc_b, A, out, acc);
  qnat_norm<<<256, 256, 0, stream>>>(out, acc, gamma, beta);
}

// Round 8
// 57.257 us; speedup vs baseline: 1.4168x; 1.1157x over previous
//
#include <hip/hip_runtime.h>
#include <math.h>

// QuantumNATHybridModel: pool(6x6) -> linear(16->4) -> 4-qubit circuit -> BatchNorm1d
// out[b,q] = r^T A_q r; A_q fixed 16x16 from qparams, r from per-sample RX angles.
// R7 lesson: at 32 waves/CU every load path (scalar/float4/pipelined/DMA) caps at
// ~2.9 TB/s => per-CU in-flight line tracking is the wall. R8: non-temporal loads
// (L1-policy bypass) on the lean R5/R6 body; everything else unchanged.

#define BATCH 65536
#define SPW 8                             // samples per wave
#define MAIN_BLOCKS (BATCH / (4 * SPW))   // 2048 blocks of 256 threads

typedef float vf4 __attribute__((ext_vector_type(4)));

// ---------------------------------------------------------------------------
// Precompute: build U (16x16 complex) from qparams, then A_q (4x16x16 real).
// Also zeroes the 8-double stats accumulator.
// ---------------------------------------------------------------------------
__global__ __launch_bounds__(256) void qnat_precompute(const float* __restrict__ qp,
                                                       float* __restrict__ A,
                                                       double* __restrict__ acc) {
  __shared__ float Ur[16][17], Ui[16][17];
  const int tid = threadIdx.x;
  if (tid >= 64 && tid < 72) acc[tid - 64] = 0.0;
  if (tid < 16) {
    const int col = tid;
    float ur[16], ui[16];
#pragma unroll
    for (int i = 0; i < 16; i++) { ur[i] = (i == col) ? 1.f : 0.f; ui[i] = 0.f; }
#pragma unroll
    for (int l = 0; l < 3; l++) {
#pragma unroll
      for (int q = 0; q < 4; q++) {
        const int b = 3 - q;  // qubit q lives on bit (3-q)
        const float ty = qp[(l * 4 + q) * 3 + 0];
        const float tz = qp[(l * 4 + q) * 3 + 1];
        const float cy = cosf(0.5f * ty), sy = sinf(0.5f * ty);
#pragma unroll
        for (int i0 = 0; i0 < 16; i0++) {
          if (((i0 >> b) & 1) == 0) {
            const int i1 = i0 | (1 << b);
            const float r0 = ur[i0], m0 = ui[i0], r1 = ur[i1], m1 = ui[i1];
            ur[i0] = cy * r0 - sy * r1;  ui[i0] = cy * m0 - sy * m1;
            ur[i1] = sy * r0 + cy * r1;  ui[i1] = sy * m0 + cy * m1;
          }
        }
        const float cz = cosf(0.5f * tz), sz = sinf(0.5f * tz);
#pragma unroll
        for (int i0 = 0; i0 < 16; i0++) {
          if (((i0 >> b) & 1) == 0) {
            const int i1 = i0 | (1 << b);
            const float r0 = ur[i0], m0 = ui[i0], r1 = ur[i1], m1 = ui[i1];
            ur[i0] = cz * r0 + sz * m0;  ui[i0] = cz * m0 - sz * r0;
            ur[i1] = cz * r1 - sz * m1;  ui[i1] = cz * m1 + sz * r1;
          }
        }
      }
      const int cb[4] = {3, 2, 1, 0};
      const int tb[4] = {2, 1, 0, 3};
#pragma unroll
      for (int e = 0; e < 4; e++) {
#pragma unroll
        for (int i = 0; i < 16; i++) {
          if (((i >> cb[e]) & 1) && (((i >> tb[e]) & 1) == 0)) {
            const int j2 = i | (1 << tb[e]);
            float t0 = ur[i]; ur[i] = ur[j2]; ur[j2] = t0;
            float t1 = ui[i]; ui[i] = ui[j2]; ui[j2] = t1;
          }
        }
      }
    }
#pragma unroll
    for (int i = 0; i < 16; i++) { Ur[i][col] = ur[i]; Ui[i][col] = ui[i]; }
  }
  __syncthreads();
  const int j = tid >> 4, k = tid & 15;
#pragma unroll
  for (int q = 0; q < 4; q++) {
    const int b = 3 - q;
    float mr = 0.f, mi = 0.f;
#pragma unroll
    for (int i = 0; i < 16; i++) {
      const float z = ((i >> b) & 1) ? -1.f : 1.f;
      const float ar = Ur[i][j], ai = Ui[i][j], br = Ur[i][k], bi = Ui[i][k];
      mr += z * (ar * br + ai * bi);
      mi += z * (ar * bi - ai * br);
    }
    const int e = (__popc((unsigned)j) - __popc((unsigned)k)) & 3;
    A[(q << 8) + tid] = (e == 0) ? mr : (e == 1) ? -mi : (e == 2) ? -mr : mi;
  }
}

// ---------------------------------------------------------------------------
// Main kernel: rolling 1-deep prefetch with NON-TEMPORAL float4 loads.
// Weights from LDS (keeps VGPR <= 64 so 32 waves/CU remains available).
// ---------------------------------------------------------------------------
__global__ __launch_bounds__(256, 4) void qnat_main(const float* __restrict__ x,
                                                    const float* __restrict__ enc_w,
                                                    const float* __restrict__ enc_b,
                                                    const float* __restrict__ A,
                                                    float* __restrict__ out,
                                                    double* __restrict__ acc) {
  __shared__ vf4 sW4[16];
  __shared__ double sAcc[4][4][2];   // [wave][q][{sum,sumsq}]
  const int tid = threadIdx.x;
  if (tid < 16) {
    const float inv36 = 1.0f / 36.0f;
    sW4[tid] = (vf4){enc_w[tid] * inv36, enc_w[16 + tid] * inv36,
                     enc_w[32 + tid] * inv36, enc_w[48 + tid] * inv36};
  }
  __syncthreads();

  const int wave = tid >> 6, lane = tid & 63;
  const int j = lane & 15;        // row of A within 16-lane group
  const int g = lane >> 4;        // which qubit's A this group owns
  const bool bit0 = lane & 1, bit1 = lane & 2;

  // Paired pool-weight LDS indices (6-col cell boundary splits any float4 2+2).
  int iX[3], iY[3];
#pragma unroll
  for (int t = 0; t < 3; t++) {
    int p0 = t * 256 + 4 * lane;
    if (p0 > 572) p0 = 572;
    const int row = p0 / 24, col = p0 - row * 24;
    const int rr = (row / 6) * 4;
    iX[t] = rr + col / 6;
    iY[t] = rr + (col + 3) / 6;
  }
  float Areg[16];
#pragma unroll
  for (int k = 0; k < 16; k++) Areg[k] = A[(g << 8) + (j << 4) + k];
  const float bq = enc_b[lane & 3];

  const int s0 = (blockIdx.x * 4 + wave) * SPW;
  double sd = 0.0, ssd = 0.0;

  auto LOADB = [&](vf4& V0, vf4& V1, vf4& V2, int S) {
    const vf4* p4 = (const vf4*)(x + (size_t)S * 576);
    V0 = __builtin_nontemporal_load(p4 + lane);
    V1 = __builtin_nontemporal_load(p4 + 64 + lane);
    if (lane < 16) V2 = __builtin_nontemporal_load(p4 + 128 + lane);
    else           V2 = (vf4){0.f, 0.f, 0.f, 0.f};
  };

  auto COMPUTE = [&](const vf4& V0, const vf4& V1, const vf4& V2, int s) {
    float a0 = 0.f, a1 = 0.f, a2 = 0.f, a3 = 0.f;
#define ACCT(V, T)                                           \
    {                                                        \
      const vf4 wX = sW4[iX[T]], wY = sW4[iY[T]];            \
      const float h0 = V[0] + V[1], h1 = V[2] + V[3];        \
      a0 = fmaf(h0, wX[0], fmaf(h1, wY[0], a0));             \
      a1 = fmaf(h0, wX[1], fmaf(h1, wY[1], a1));             \
      a2 = fmaf(h0, wX[2], fmaf(h1, wY[2], a2));             \
      a3 = fmaf(h0, wX[3], fmaf(h1, wY[3], a3));             \
    }
    ACCT(V0, 0) ACCT(V1, 1) ACCT(V2, 2)
#undef ACCT

    // Rotation fold: distribute the 4 angle sums across lane&3 while reducing.
    float snd, rcv;
    snd = bit0 ? a0 : a1; rcv = __shfl_xor(snd, 1);
    float Af = (bit0 ? a1 : a0) + rcv;
    snd = bit0 ? a2 : a3; rcv = __shfl_xor(snd, 1);
    float Bf = (bit0 ? a3 : a2) + rcv;
    snd = bit1 ? Af : Bf; rcv = __shfl_xor(snd, 2);
    float Cf = (bit1 ? Bf : Af) + rcv;
    Cf += __shfl_xor(Cf, 4);
    Cf += __shfl_xor(Cf, 8);
    Cf += __shfl_xor(Cf, 16);
    Cf += __shfl_xor(Cf, 32);                    // theta_{lane&3}

    float sm, cm;
    __sincosf(0.5f * (Cf + bq), &sm, &cm);       // one sincos per lane

    const int base = lane & ~3;
    const float c0 = __shfl(cm, base + 0), s0_ = __shfl(sm, base + 0);
    const float c1 = __shfl(cm, base + 1), s1_ = __shfl(sm, base + 1);
    const float c2 = __shfl(cm, base + 2), s2_ = __shfl(sm, base + 2);
    const float c3 = __shfl(cm, base + 3), s3_ = __shfl(sm, base + 3);

    const float p01[4] = {c0 * c1, c0 * s1_, s0_ * c1, s0_ * s1_};
    const float p23[4] = {c2 * c3, c2 * s3_, s2_ * c3, s2_ * s3_};
    float inner = 0.f;
#pragma unroll
    for (int hi = 0; hi < 4; hi++) {
      float sh = 0.f;
#pragma unroll
      for (int lo = 0; lo < 4; lo++) sh = fmaf(Areg[4 * hi + lo], p23[lo], sh);
      inner = fmaf(p01[hi], sh, inner);
    }
    const float rj = ((j & 8) ? s0_ : c0) * ((j & 4) ? s1_ : c1) *
                     ((j & 2) ? s2_ : c2) * ((j & 1) ? s3_ : c3);
    float v = inner * rj;
    v += __shfl_xor(v, 1);
    v += __shfl_xor(v, 2);
    v += __shfl_xor(v, 4);
    v += __shfl_xor(v, 8);
    if (j == 0) {
      out[(size_t)s * 4 + g] = v;
      sd += (double)v;
      ssd = fma((double)v, (double)v, ssd);
    }
  };

  // Rolling 1-deep pipeline, statically named buffers (loads issue before compute).
  vf4 A0, A1, A2, B0, B1, B2;
  LOADB(A0, A1, A2, s0 + 0);
  LOADB(B0, B1, B2, s0 + 1); COMPUTE(A0, A1, A2, s0 + 0);
  LOADB(A0, A1, A2, s0 + 2); COMPUTE(B0, B1, B2, s0 + 1);
  LOADB(B0, B1, B2, s0 + 3); COMPUTE(A0, A1, A2, s0 + 2);
  LOADB(A0, A1, A2, s0 + 4); COMPUTE(B0, B1, B2, s0 + 3);
  LOADB(B0, B1, B2, s0 + 5); COMPUTE(A0, A1, A2, s0 + 4);
  LOADB(A0, A1, A2, s0 + 6); COMPUTE(B0, B1, B2, s0 + 5);
  LOADB(B0, B1, B2, s0 + 7); COMPUTE(A0, A1, A2, s0 + 6);
  COMPUTE(B0, B1, B2, s0 + 7);

  if (j == 0) { sAcc[wave][g][0] = sd; sAcc[wave][g][1] = ssd; }
  __syncthreads();
  if (tid < 8) {  // tid = m*4 + q
    const int q = tid & 3, m = tid >> 2;
    const double t = sAcc[0][q][m] + sAcc[1][q][m] + sAcc[2][q][m] + sAcc[3][q][m];
    atomicAdd(&acc[m * 4 + q], t);
  }
}

// ---------------------------------------------------------------------------
// Normalize in place: out = (raw - mean)/sqrt(var+eps)*gamma + beta
// ---------------------------------------------------------------------------
__global__ __launch_bounds__(256) void qnat_norm(float* __restrict__ out,
                                                 const double* __restrict__ acc,
                                                 const float* __restrict__ gamma,
                                                 const float* __restrict__ beta) {
  __shared__ float sMean[4], sScale[4], sBeta[4];
  const int tid = threadIdx.x;
  if (tid < 4) {
    const double n = (double)BATCH;
    const double mean = acc[tid] / n;
    const double var = acc[4 + tid] / n - mean * mean;
    const double inv = 1.0 / sqrt(var + 1e-5);
    sMean[tid] = (float)mean;
    sScale[tid] = (float)(gamma[tid] * inv);
    sBeta[tid] = beta[tid];
  }
  __syncthreads();
  const size_t i = (size_t)blockIdx.x * 256 + tid;  // 65536 float4s, 256 blocks
  float4 v = ((const float4*)out)[i];
  v.x = (v.x - sMean[0]) * sScale[0] + sBeta[0];
  v.y = (v.y - sMean[1]) * sScale[1] + sBeta[1];
  v.z = (v.z - sMean[2]) * sScale[2] + sBeta[2];
  v.w = (v.w - sMean[3]) * sScale[3] + sBeta[3];
  ((float4*)out)[i] = v;
}

extern "C" void kernel_launch(void* const* d_in, const int* in_sizes, int n_in,
                              void* d_out, int out_size, void* d_ws, size_t ws_size,
                              hipStream_t stream) {
  const float* x       = (const float*)d_in[0];
  const float* enc_w   = (const float*)d_in[1];
  const float* enc_b   = (const float*)d_in[2];
  const float* qparams = (const float*)d_in[3];
  const float* gamma   = (const float*)d_in[4];
  const float* beta    = (const float*)d_in[5];
  float* out = (float*)d_out;

  float* A = (float*)d_ws;                          // 4*16*16 floats = 4 KB
  double* acc = (double*)((char*)d_ws + 4096);      // 8 doubles

  qnat_precompute<<<1, 256, 0, stream>>>(qparams, A, acc);
  qnat_main<<<MAIN_BLOCKS, 256, 0, stream>>>(x, enc_w, enc_b, A, out, acc);
  qnat_norm<<<256, 256, 0, stream>>>(out, acc, gamma, beta);
}